// Round 1
// baseline (192.602 us; speedup 1.0000x reference)
//
#include <hip/hip_runtime.h>

__device__ __forceinline__ float shfl64c(float v, int src) {
    src = src < 0 ? 0 : (src > 63 ? 63 : src);
    return __shfl(v, src, 64);
}

__global__ __launch_bounds__(256) void apply_area_kernel(
    const float* __restrict__ img_g,
    const float* __restrict__ mn_g,
    const float* __restrict__ mo_g,
    float* __restrict__ out,
    int B)
{
    const int wave = threadIdx.x >> 6;
    const int lane = threadIdx.x & 63;
    const int b = blockIdx.x * 4 + wave;
    if (b >= B) return;

    const int r = lane >> 2;   // row 0..15 of the 16x16 tile
    const int k = lane & 3;    // column group (cols 4k..4k+3)

    // ---- loads (fully coalesced float4) ----
    const float4 iv = reinterpret_cast<const float4*>(img_g + (size_t)b * 256)[lane];
    float im[4] = {iv.x, iv.y, iv.z, iv.w};

    // mc = interleave(mn, mo) by rows: row 2i = mn[i], row 2i+1 = mo[i]
    float4 mv;
    if ((r & 1) == 0)
        mv = reinterpret_cast<const float4*>(mn_g + (size_t)b * 128)[(r >> 1) * 4 + k];
    else
        mv = reinterpret_cast<const float4*>(mo_g + (size_t)b * 128)[(r >> 1) * 4 + k];
    float mc[4] = {mv.x, mv.y, mv.z, mv.w};

    // ---- in-wave neighbor exchange ----
    float m_rm1[4], m_rp1[4], m_rp2[4], m_rm2[4], m_rp3[4], i_rm1[4], i_rp1[4];
#pragma unroll
    for (int j = 0; j < 4; ++j) {
        m_rm1[j] = shfl64c(mc[j], lane - 4);   // mc row r-1
        m_rp1[j] = shfl64c(mc[j], lane + 4);   // mc row r+1
        m_rm2[j] = shfl64c(mc[j], lane - 8);   // mc row r-2
        m_rp2[j] = shfl64c(mc[j], lane + 8);   // mc row r+2
        m_rp3[j] = shfl64c(mc[j], lane + 12);  // mc row r+3
        i_rm1[j] = shfl64c(im[j], lane - 4);   // img row r-1
        i_rp1[j] = shfl64c(im[j], lane + 4);   // img row r+1
    }
    float nb0 = shfl64c(mc[0], lane + 1);  // next col-group, col 4k+4
    float nb1 = shfl64c(mc[1], lane + 1);  // col 4k+5
    float pb2 = shfl64c(mc[2], lane - 1);  // prev col-group, col 4k-2
    float pb3 = shfl64c(mc[3], lane - 1);  // col 4k-1

    float c_acc = 0.f, r_acc = 0.f, e_acc = 0.f, a_acc = 0.f, smc = 0.f, smi = 0.f;

    // ---- consistency (8x16 grid; even mc rows hold mn row i=r/2) ----
    // g[i,j] = 0.5*(mo[i+1,j]-mo[i-1,j]) with zero pad; mo[i] = mc row r+1,
    // mo[i-1] = mc row r-1, mo[i+1] = mc row r+3.
    if ((r & 1) == 0) {
        const bool hm = (r >= 2);    // i > 0
        const bool hp = (r <= 12);   // i < 7
#pragma unroll
        for (int j = 0; j < 4; ++j) {
            float mo_i   = m_rp1[j];
            float mo_im1 = hm ? m_rm1[j] : 0.f;
            float mo_ip1 = hp ? m_rp3[j] : 0.f;
            float g = 0.5f * (mo_ip1 - mo_im1);
            c_acc += fmaxf(mc[j] - 5.f * (g * g + mo_i), 0.f);
        }
    }

#pragma unroll
    for (int j = 0; j < 4; ++j) {
        // edge: grad along rows, boundary rows use one-sided diff
        float gi = (r == 0) ? (i_rp1[j] - im[j])
                 : (r == 15) ? (im[j] - i_rm1[j])
                 : 0.5f * (i_rp1[j] - i_rm1[j]);
        float gm = (r == 0) ? (m_rp1[j] - mc[j])
                 : (r == 15) ? (mc[j] - m_rm1[j])
                 : 0.5f * (m_rp1[j] - m_rm1[j]);
        float d = gi - gm;
        e_acc += 0.5f * d * d * gi;
        // rounding: -(2mc-1)^2, accumulate positive part
        float tw = 2.f * mc[j] - 1.f;
        r_acc += tw * tw;
        // avg_cov vs analytic diamond: |7-r| <= c <= 14-|7-r|, zero row/col 15
        int c = (k << 2) + j;
        int ab = (r > 7) ? (r - 7) : (7 - r);
        float dia = (r < 15 && c >= ab && c <= 14 - ab) ? 1.f : 0.f;
        float dd = mc[j] - dia;
        a_acc += 0.5f * dd * dd;
        // sums for out_image
        smc += mc[j];
        smi += mc[j] * im[j];
    }

    // ---- the 4 translations of mc (zero-padded shifts by 2) ----
    float t0[4], t1[4], t2[4], t3[4];
#pragma unroll
    for (int j = 0; j < 4; ++j) {
        t0[j] = (r < 14) ? m_rp2[j] : 0.f;  // rows shifted up:    t0[r,c]=mc[r+2,c]
        t1[j] = (r >= 2) ? m_rm2[j] : 0.f;  // rows shifted down:  t1[r,c]=mc[r-2,c]
    }
    t2[0] = mc[2]; t2[1] = mc[3];                       // cols shifted left
    t2[2] = (k < 3) ? nb0 : 0.f; t2[3] = (k < 3) ? nb1 : 0.f;
    t3[0] = (k > 0) ? pb2 : 0.f; t3[1] = (k > 0) ? pb3 : 0.f;  // cols shifted right
    t3[2] = mc[0]; t3[3] = mc[1];

    float st0=0,st1=0,st2=0,st3=0, mt0=0,mt1=0,mt2=0,mt3=0;
#pragma unroll
    for (int j = 0; j < 4; ++j) {
        st0 += t0[j]; mt0 += t0[j] * im[j];
        st1 += t1[j]; mt1 += t1[j] * im[j];
        st2 += t2[j]; mt2 += t2[j] * im[j];
        st3 += t3[j]; mt3 += t3[j] * im[j];
    }

    // ---- phase A butterfly reduce (14 values, 6 stages) ----
#pragma unroll
    for (int o = 32; o; o >>= 1) {
        c_acc += __shfl_xor(c_acc, o, 64);
        r_acc += __shfl_xor(r_acc, o, 64);
        e_acc += __shfl_xor(e_acc, o, 64);
        a_acc += __shfl_xor(a_acc, o, 64);
        smc   += __shfl_xor(smc,   o, 64);
        smi   += __shfl_xor(smi,   o, 64);
        st0 += __shfl_xor(st0, o, 64); mt0 += __shfl_xor(mt0, o, 64);
        st1 += __shfl_xor(st1, o, 64); mt1 += __shfl_xor(mt1, o, 64);
        st2 += __shfl_xor(st2, o, 64); mt2 += __shfl_xor(mt2, o, 64);
        st3 += __shfl_xor(st3, o, 64); mt3 += __shfl_xor(mt3, o, 64);
    }

    // ---- phase B: variances of the translated-mask features ----
    const float mean0 = mt0 / st0, mean1 = mt1 / st1, mean2 = mt2 / st2, mean3 = mt3 / st3;
    float v0 = 0.f, v1 = 0.f, v2 = 0.f, v3 = 0.f;
#pragma unroll
    for (int j = 0; j < 4; ++j) {
        float d0 = (t0[j] * im[j] - mean0) * t0[j]; v0 += d0 * d0;
        float d1 = (t1[j] * im[j] - mean1) * t1[j]; v1 += d1 * d1;
        float d2 = (t2[j] * im[j] - mean2) * t2[j]; v2 += d2 * d2;
        float d3 = (t3[j] * im[j] - mean3) * t3[j]; v3 += d3 * d3;
    }
#pragma unroll
    for (int o = 32; o; o >>= 1) {
        v0 += __shfl_xor(v0, o, 64);
        v1 += __shfl_xor(v1, o, 64);
        v2 += __shfl_xor(v2, o, 64);
        v3 += __shfl_xor(v3, o, 64);
    }

    const float scale = smi / smc;

    // ---- stores ----
    reinterpret_cast<float4*>(out)[(size_t)b * 64 + lane] = mv;  // mc
    float4 ov = make_float4(mc[0] * scale, mc[1] * scale, mc[2] * scale, mc[3] * scale);
    reinterpret_cast<float4*>(out + (size_t)B * 256)[(size_t)b * 64 + lane] = ov;  // out_image

    if (lane == 0) {
        float var0 = v0 / st0, var1 = v1 / st1, var2 = v2 / st2, var3 = v3 / st3;
        float fm = 0.25f * (mean0 + mean1 + mean2 + mean3);
        float dm0 = mean0 - fm, dm1 = mean1 - fm, dm2 = mean2 - fm, dm3 = mean3 - fm;
        float vm = 0.25f * (dm0*dm0 + dm1*dm1 + dm2*dm2 + dm3*dm3);
        float fv = 0.25f * (var0 + var1 + var2 + var3);
        float dv0 = var0 - fv, dv1 = var1 - fv, dv2 = var2 - fv, dv3 = var3 - fv;
        float vv = 0.25f * (dv0*dv0 + dv1*dv1 + dv2*dv2 + dv3*dv3);

        float* s = out + (size_t)B * 512;
        s[b]                 = c_acc * (1.f / 128.f);   // consistency
        s[(size_t)B + b]     = -r_acc * (1.f / 256.f);  // rounding
        s[2*(size_t)B + b]   = 0.5f * (vm + vv);        // fvar
        s[3*(size_t)B + b]   = e_acc * (1.f / 256.f);   // edge
        s[4*(size_t)B + b]   = a_acc * (1.f / 256.f);   // avg_cov
    }
}

extern "C" void kernel_launch(void* const* d_in, const int* in_sizes, int n_in,
                              void* d_out, int out_size, void* d_ws, size_t ws_size,
                              hipStream_t stream) {
    const float* img = (const float*)d_in[0];
    const float* mn  = (const float*)d_in[1];
    const float* mo  = (const float*)d_in[2];
    float* out = (float*)d_out;
    const int B = in_sizes[0] / 256;
    const int blocks = (B + 3) / 4;
    apply_area_kernel<<<blocks, 256, 0, stream>>>(img, mn, mo, out, B);
}

// Round 2
// 105.234 us; speedup vs baseline: 1.8302x; 1.8302x over previous
//
#include <hip/hip_runtime.h>

// DPP move: compile-time control, bound_ctrl=1 (out-of-range lanes read 0)
template<int CTRL>
__device__ __forceinline__ float dppf(float v) {
    return __int_as_float(__builtin_amdgcn_update_dpp(
        0, __float_as_int(v), CTRL, 0xF, 0xF, true));
}

// Sum across each 16-lane group (DPP row); result valid on ALL 16 lanes.
// xor1 (quad_perm [1,0,3,2]), xor2 (quad_perm [2,3,0,1]),
// row_half_mirror (pairs 8-blocks), row_mirror (pairs 16-halves).
__device__ __forceinline__ float bfly16(float v) {
    v += dppf<0xB1>(v);
    v += dppf<0x4E>(v);
    v += dppf<0x141>(v);
    v += dppf<0x140>(v);
    return v;
}

__global__ __launch_bounds__(256) void apply_area_kernel(
    const float* __restrict__ img_g,
    const float* __restrict__ mn_g,
    const float* __restrict__ mo_g,
    float* __restrict__ out,
    int B)
{
    const int lane = threadIdx.x & 63;
    const int w    = threadIdx.x >> 6;
    const int q    = lane >> 4;      // batch within wave (4 per wave)
    const int c    = lane & 15;      // column owned by this lane
    const int b    = blockIdx.x * 16 + w * 4 + q;
    if (b >= B) return;

    // ---- strided loads: lane owns column c of its batch ----
    // each dword-load instruction touches exactly 4 full 64B lines (4 batches)
    const float* imp = img_g + (size_t)b * 256 + c;
    const float* mnp = mn_g  + (size_t)b * 128 + c;
    const float* mop = mo_g  + (size_t)b * 128 + c;

    float im[16], mc[16];
#pragma unroll
    for (int r = 0; r < 16; ++r) im[r] = imp[r * 16];
#pragma unroll
    for (int i = 0; i < 8; ++i) {     // mc row 2i = mn[i], row 2i+1 = mo[i]
        mc[2 * i]     = mnp[i * 16];
        mc[2 * i + 1] = mop[i * 16];
    }

    // ---- consistency: all along rows -> in-register ----
    float c_acc = 0.f;
#pragma unroll
    for (int i = 0; i < 8; ++i) {
        float mo_i = mc[2 * i + 1];
        float mo_m = (i > 0) ? mc[2 * i - 1] : 0.f;
        float mo_p = (i < 7) ? mc[2 * i + 3] : 0.f;
        float g = 0.5f * (mo_p - mo_m);
        c_acc += fmaxf(mc[2 * i] - 5.f * (g * g + mo_i), 0.f);
    }

    // ---- edge / rounding / avg_cov / column sums ----
    float e_acc = 0.f, r_acc = 0.f, a_acc = 0.f, smi = 0.f, S1 = 0.f, S2 = 0.f;
#pragma unroll
    for (int r = 0; r < 16; ++r) {
        float gi = (r == 0)  ? im[1] - im[0]
                 : (r == 15) ? im[15] - im[14]
                 : 0.5f * (im[r + 1] - im[r - 1]);
        float gm = (r == 0)  ? mc[1] - mc[0]
                 : (r == 15) ? mc[15] - mc[14]
                 : 0.5f * (mc[r + 1] - mc[r - 1]);
        float d = gi - gm;
        e_acc += 0.5f * d * d * gi;
        float tw = 2.f * mc[r] - 1.f;
        r_acc += tw * tw;
        int abr = (r > 7) ? r - 7 : 7 - r;
        float dia = (r < 15 && c >= abr && c <= 14 - abr) ? 1.f : 0.f;
        float dd = mc[r] - dia;
        a_acc += 0.5f * dd * dd;
        S1 += mc[r];
        S2 += mc[r] * mc[r];
        smi += mc[r] * im[r];
    }

    // ---- 4 translations: B=Σt·im, D=Σt³·im, E=Σt⁴·im² (A,C derived) ----
    float B0 = 0, D0 = 0, E0 = 0, B1 = 0, D1 = 0, E1 = 0;
    float B2 = 0, D2 = 0, E2 = 0, B3 = 0, D3 = 0, E3 = 0;
#pragma unroll
    for (int r = 0; r < 16; ++r) {
        float t0v = (r < 14) ? mc[r + 2] : 0.f;   // rows from r+2 (in-register)
        float t1v = (r >= 2) ? mc[r - 2] : 0.f;   // rows from r-2 (in-register)
        float t2v = dppf<0x102>(mc[r]);           // row_shl:2 -> col c+2, 0-pad
        float t3v = dppf<0x112>(mc[r]);           // row_shr:2 -> col c-2, 0-pad
#define ACC(t, Bx, Dx, Ex) { float mi_ = (t) * im[r]; float tt_ = (t) * (t); \
        Bx += mi_; Dx = fmaf(tt_, mi_, Dx); float tm_ = (t) * mi_; Ex = fmaf(tm_, tm_, Ex); }
        ACC(t0v, B0, D0, E0)
        ACC(t1v, B1, D1, E1)
        ACC(t2v, B2, D2, E2)
        ACC(t3v, B3, D3, E3)
#undef ACC
    }
    // A=Σt, C=Σt² per-lane partials from column sums
    float A0 = S1 - mc[0] - mc[1];
    float C0 = S2 - mc[0] * mc[0] - mc[1] * mc[1];
    float A1 = S1 - mc[14] - mc[15];
    float C1 = S2 - mc[14] * mc[14] - mc[15] * mc[15];
    float A2 = dppf<0x102>(S1), C2 = dppf<0x102>(S2);
    float A3 = dppf<0x112>(S1), C3 = dppf<0x112>(S2);

    // ---- 26 group reductions, all on the VALU pipe (DPP), no DS ----
    c_acc = bfly16(c_acc); r_acc = bfly16(r_acc);
    e_acc = bfly16(e_acc); a_acc = bfly16(a_acc);
    float smc = bfly16(S1); smi = bfly16(smi);
    A0 = bfly16(A0); A1 = bfly16(A1); A2 = bfly16(A2); A3 = bfly16(A3);
    B0 = bfly16(B0); B1 = bfly16(B1); B2 = bfly16(B2); B3 = bfly16(B3);
    C0 = bfly16(C0); C1 = bfly16(C1); C2 = bfly16(C2); C3 = bfly16(C3);
    D0 = bfly16(D0); D1 = bfly16(D1); D2 = bfly16(D2); D3 = bfly16(D3);
    E0 = bfly16(E0); E1 = bfly16(E1); E2 = bfly16(E2); E3 = bfly16(E3);

    // ---- finish (all lanes have totals) ----
    const float scale = smi / smc;

    float* mco = out + (size_t)b * 256 + c;
    float* oio = out + (size_t)B * 256 + (size_t)b * 256 + c;
#pragma unroll
    for (int r = 0; r < 16; ++r) {
        mco[r * 16] = mc[r];
        oio[r * 16] = mc[r] * scale;
    }

    if (c == 0) {
        float m0 = B0 / A0, m1 = B1 / A1, m2 = B2 / A2, m3 = B3 / A3;
        float v0 = (E0 - 2.f * m0 * D0 + m0 * m0 * C0) / A0;
        float v1 = (E1 - 2.f * m1 * D1 + m1 * m1 * C1) / A1;
        float v2 = (E2 - 2.f * m2 * D2 + m2 * m2 * C2) / A2;
        float v3 = (E3 - 2.f * m3 * D3 + m3 * m3 * C3) / A3;

        float fm = 0.25f * (m0 + m1 + m2 + m3);
        float dm0 = m0 - fm, dm1 = m1 - fm, dm2 = m2 - fm, dm3 = m3 - fm;
        float vm = 0.25f * (dm0 * dm0 + dm1 * dm1 + dm2 * dm2 + dm3 * dm3);
        float fv = 0.25f * (v0 + v1 + v2 + v3);
        float dv0 = v0 - fv, dv1 = v1 - fv, dv2 = v2 - fv, dv3 = v3 - fv;
        float vv = 0.25f * (dv0 * dv0 + dv1 * dv1 + dv2 * dv2 + dv3 * dv3);

        float* s = out + (size_t)B * 512;
        s[b]                 = c_acc * (1.f / 128.f);   // consistency
        s[(size_t)B + b]     = -r_acc * (1.f / 256.f);  // rounding
        s[2 * (size_t)B + b] = 0.5f * (vm + vv);        // fvar
        s[3 * (size_t)B + b] = e_acc * (1.f / 256.f);   // edge
        s[4 * (size_t)B + b] = a_acc * (1.f / 256.f);   // avg_cov
    }
}

extern "C" void kernel_launch(void* const* d_in, const int* in_sizes, int n_in,
                              void* d_out, int out_size, void* d_ws, size_t ws_size,
                              hipStream_t stream) {
    const float* img = (const float*)d_in[0];
    const float* mn  = (const float*)d_in[1];
    const float* mo  = (const float*)d_in[2];
    float* out = (float*)d_out;
    const int B = in_sizes[0] / 256;
    const int blocks = (B + 15) / 16;   // 16 batches per 256-thread block
    apply_area_kernel<<<blocks, 256, 0, stream>>>(img, mn, mo, out, B);
}

// Round 4
// 103.056 us; speedup vs baseline: 1.8689x; 1.0211x over previous
//
#include <hip/hip_runtime.h>

typedef float vf2 __attribute__((ext_vector_type(2)));

// DPP move: compile-time control, bound_ctrl=1 (out-of-range lanes read 0)
template<int CTRL>
__device__ __forceinline__ float dppf(float v) {
    return __int_as_float(__builtin_amdgcn_update_dpp(
        0, __float_as_int(v), CTRL, 0xF, 0xF, true));
}

// Sum across each 8-lane half-row; result valid on ALL 8 lanes.
__device__ __forceinline__ float bfly8(float v) {
    v += dppf<0xB1>(v);    // quad_perm [1,0,3,2]  (xor 1)
    v += dppf<0x4E>(v);    // quad_perm [2,3,0,1]  (xor 2)
    v += dppf<0x141>(v);   // row_half_mirror      (joins the two quads)
    return v;
}

__global__ __launch_bounds__(256) void apply_area_kernel(
    const float* __restrict__ img_g,
    const float* __restrict__ mn_g,
    const float* __restrict__ mo_g,
    float* __restrict__ out,
    int B)
{
    const int lane = threadIdx.x & 63;
    const int w    = threadIdx.x >> 6;
    const int q    = lane >> 3;      // batch within wave (8 per wave)
    const int l    = lane & 7;       // column-pair: owns cols 2l, 2l+1
    const int b    = blockIdx.x * 32 + w * 8 + q;
    if (b >= B) return;

    const vf2* im2 = reinterpret_cast<const vf2*>(img_g) + (size_t)b * 128 + l;
    const vf2* mn2 = reinterpret_cast<const vf2*>(mn_g)  + (size_t)b * 64  + l;
    const vf2* mo2 = reinterpret_cast<const vf2*>(mo_g)  + (size_t)b * 64  + l;

    float imx[16], imy[16], mcx[16], mcy[16];
#pragma unroll
    for (int r = 0; r < 16; ++r) { vf2 v = im2[r * 8]; imx[r] = v.x; imy[r] = v.y; }
#pragma unroll
    for (int i = 0; i < 8; ++i) {   // mc row 2i = mn[i], row 2i+1 = mo[i]
        vf2 a = mn2[i * 8]; mcx[2*i]   = a.x; mcy[2*i]   = a.y;
        vf2 o = mo2[i * 8]; mcx[2*i+1] = o.x; mcy[2*i+1] = o.y;
    }

    // ---- consistency (rows in-register) ----
    float c_acc = 0.f;
#pragma unroll
    for (int i = 0; i < 8; ++i) {
        float mx_m = (i > 0) ? mcx[2*i-1] : 0.f, my_m = (i > 0) ? mcy[2*i-1] : 0.f;
        float mx_p = (i < 7) ? mcx[2*i+3] : 0.f, my_p = (i < 7) ? mcy[2*i+3] : 0.f;
        float gx = 0.5f * (mx_p - mx_m), gy = 0.5f * (my_p - my_m);
        c_acc += fmaxf(mcx[2*i] - 5.f * (gx*gx + mcx[2*i+1]), 0.f);
        c_acc += fmaxf(mcy[2*i] - 5.f * (gy*gy + mcy[2*i+1]), 0.f);
    }

    // ---- edge / rounding / avg_cov / column-pair sums ----
    float e_acc = 0.f, r_acc = 0.f, a_acc = 0.f, smi = 0.f, S1 = 0.f, S2 = 0.f;
    const int c0 = 2 * l, c1 = 2 * l + 1;
#pragma unroll
    for (int r = 0; r < 16; ++r) {
        int abr = (r > 7) ? r - 7 : 7 - r;
        bool drow = (r < 15);
#define COMP(imA, mcA, cc) { \
        float gi = (r == 0)  ? imA[1] - imA[0] \
                 : (r == 15) ? imA[15] - imA[14] \
                 : 0.5f * (imA[r + 1] - imA[r - 1]); \
        float gm = (r == 0)  ? mcA[1] - mcA[0] \
                 : (r == 15) ? mcA[15] - mcA[14] \
                 : 0.5f * (mcA[r + 1] - mcA[r - 1]); \
        float d = gi - gm; e_acc += 0.5f * d * d * gi; \
        float tw = 2.f * mcA[r] - 1.f; r_acc += tw * tw; \
        float dia = (drow && (cc) >= abr && (cc) <= 14 - abr) ? 1.f : 0.f; \
        float dd = mcA[r] - dia; a_acc += 0.5f * dd * dd; \
        S1 += mcA[r]; S2 += mcA[r] * mcA[r]; smi += mcA[r] * imA[r]; }
        COMP(imx, mcx, c0)
        COMP(imy, mcy, c1)
#undef COMP
    }

    // ---- 4 translations: B=Σt·im, D=Σt³·im, E=Σ(t²·im)² ----
    const float mz7 = (l == 7) ? 0.f : 1.f;   // col-shift-left batch boundary
    const float mz0 = (l == 0) ? 0.f : 1.f;   // col-shift-right batch boundary
    float B0=0,D0=0,E0=0, B1=0,D1=0,E1=0, B2=0,D2=0,E2=0, B3=0,D3=0,E3=0;
#pragma unroll
    for (int r = 0; r < 16; ++r) {
        float t0x = (r < 14) ? mcx[r+2] : 0.f, t0y = (r < 14) ? mcy[r+2] : 0.f;
        float t1x = (r >= 2) ? mcx[r-2] : 0.f, t1y = (r >= 2) ? mcy[r-2] : 0.f;
        float t2x = dppf<0x101>(mcx[r]) * mz7, t2y = dppf<0x101>(mcy[r]) * mz7;
        float t3x = dppf<0x111>(mcx[r]) * mz0, t3y = dppf<0x111>(mcy[r]) * mz0;
#define ACC2(tx, ty, Bx, Dx, Ex) { \
        float mix_ = (tx) * imx[r], miy_ = (ty) * imy[r]; \
        Bx += mix_ + miy_; \
        Dx += (tx)*(tx)*mix_ + (ty)*(ty)*miy_; \
        float ax_ = (tx)*mix_, ay_ = (ty)*miy_; \
        Ex += ax_*ax_ + ay_*ay_; }
        ACC2(t0x, t0y, B0, D0, E0)
        ACC2(t1x, t1y, B1, D1, E1)
        ACC2(t2x, t2y, B2, D2, E2)
        ACC2(t3x, t3y, B3, D3, E3)
#undef ACC2
    }
    // A=Σt, C=Σt² from column-pair sums
    float A0 = S1 - (mcx[0] + mcy[0] + mcx[1] + mcy[1]);
    float C0 = S2 - (mcx[0]*mcx[0] + mcy[0]*mcy[0] + mcx[1]*mcx[1] + mcy[1]*mcy[1]);
    float A1 = S1 - (mcx[14] + mcy[14] + mcx[15] + mcy[15]);
    float C1 = S2 - (mcx[14]*mcx[14] + mcy[14]*mcy[14] + mcx[15]*mcx[15] + mcy[15]*mcy[15]);
    float A2 = dppf<0x101>(S1) * mz7, C2 = dppf<0x101>(S2) * mz7;
    float A3 = dppf<0x111>(S1) * mz0, C3 = dppf<0x111>(S2) * mz0;

    // ---- 26 half-row reductions, all DPP on the VALU pipe ----
    c_acc = bfly8(c_acc); r_acc = bfly8(r_acc);
    e_acc = bfly8(e_acc); a_acc = bfly8(a_acc);
    float smc = bfly8(S1); smi = bfly8(smi);
    A0 = bfly8(A0); A1 = bfly8(A1); A2 = bfly8(A2); A3 = bfly8(A3);
    B0 = bfly8(B0); B1 = bfly8(B1); B2 = bfly8(B2); B3 = bfly8(B3);
    C0 = bfly8(C0); C1 = bfly8(C1); C2 = bfly8(C2); C3 = bfly8(C3);
    D0 = bfly8(D0); D1 = bfly8(D1); D2 = bfly8(D2); D3 = bfly8(D3);
    E0 = bfly8(E0); E1 = bfly8(E1); E2 = bfly8(E2); E3 = bfly8(E3);

    // ---- stores (nontemporal: keep the streamed output out of L2/L3) ----
    const float scale = smi / smc;
    vf2* mco = reinterpret_cast<vf2*>(out) + (size_t)b * 128 + l;
    vf2* oio = reinterpret_cast<vf2*>(out) + (size_t)B * 128 + (size_t)b * 128 + l;
#pragma unroll
    for (int r = 0; r < 16; ++r) {
        vf2 mv; mv.x = mcx[r]; mv.y = mcy[r];
        vf2 ov; ov.x = mcx[r] * scale; ov.y = mcy[r] * scale;
        __builtin_nontemporal_store(mv, mco + r * 8);
        __builtin_nontemporal_store(ov, oio + r * 8);
    }

    if (l == 0) {
        float m0 = B0 / A0, m1 = B1 / A1, m2 = B2 / A2, m3 = B3 / A3;
        float v0 = (E0 - 2.f * m0 * D0 + m0 * m0 * C0) / A0;
        float v1 = (E1 - 2.f * m1 * D1 + m1 * m1 * C1) / A1;
        float v2 = (E2 - 2.f * m2 * D2 + m2 * m2 * C2) / A2;
        float v3 = (E3 - 2.f * m3 * D3 + m3 * m3 * C3) / A3;

        float fm = 0.25f * (m0 + m1 + m2 + m3);
        float dm0 = m0 - fm, dm1 = m1 - fm, dm2 = m2 - fm, dm3 = m3 - fm;
        float vm = 0.25f * (dm0*dm0 + dm1*dm1 + dm2*dm2 + dm3*dm3);
        float fv = 0.25f * (v0 + v1 + v2 + v3);
        float dv0 = v0 - fv, dv1 = v1 - fv, dv2 = v2 - fv, dv3 = v3 - fv;
        float vv = 0.25f * (dv0*dv0 + dv1*dv1 + dv2*dv2 + dv3*dv3);

        float* s = out + (size_t)B * 512;
        __builtin_nontemporal_store(c_acc * (1.f / 128.f), s + b);                 // consistency
        __builtin_nontemporal_store(-r_acc * (1.f / 256.f), s + (size_t)B + b);    // rounding
        __builtin_nontemporal_store(0.5f * (vm + vv), s + 2*(size_t)B + b);        // fvar
        __builtin_nontemporal_store(e_acc * (1.f / 256.f), s + 3*(size_t)B + b);   // edge
        __builtin_nontemporal_store(a_acc * (1.f / 256.f), s + 4*(size_t)B + b);   // avg_cov
    }
}

extern "C" void kernel_launch(void* const* d_in, const int* in_sizes, int n_in,
                              void* d_out, int out_size, void* d_ws, size_t ws_size,
                              hipStream_t stream) {
    const float* img = (const float*)d_in[0];
    const float* mn  = (const float*)d_in[1];
    const float* mo  = (const float*)d_in[2];
    float* out = (float*)d_out;
    const int B = in_sizes[0] / 256;
    const int blocks = (B + 31) / 32;   // 32 batches per 256-thread block
    apply_area_kernel<<<blocks, 256, 0, stream>>>(img, mn, mo, out, B);
}